// Round 6
// baseline (244.698 us; speedup 1.0000x reference)
//
#include <hip/hip_runtime.h>

#define NPTS_C 32            // channels
#define NTAPS 27             // 3x3x3
#define KEY_WORDS (1u << 20) // 2^25 keys / 32 bits
#define SCAN_BLOCKS 1024     // KEY_WORDS / 1024 words per block

typedef float f32x4 __attribute__((ext_vector_type(4))); // native vec for nontemporal store

__device__ __forceinline__ unsigned make_key(int b, int x, int y, int z) {
    return ((((unsigned)b << 8 | (unsigned)x) << 8 | (unsigned)y) << 8) | (unsigned)z;
}

// 1) scatter occupancy bits
__global__ void k_scatter_bits(const int4* __restrict__ coords, unsigned* __restrict__ bitmask, int n) {
    int i = blockIdx.x * blockDim.x + threadIdx.x;
    if (i >= n) return;
    int4 co = coords[i];
    unsigned key = make_key(co.x, co.y, co.z, co.w);
    atomicOr(&bitmask[key >> 5], 1u << (key & 31u));
}

// 2) per-block (1024 words) popcount sums
__global__ void k_popc_sums(const uint4* __restrict__ bm4, unsigned* __restrict__ blockSums) {
    int t = threadIdx.x;
    uint4 w = bm4[blockIdx.x * 256 + t];
    unsigned s = __popc(w.x) + __popc(w.y) + __popc(w.z) + __popc(w.w);
    for (int off = 32; off > 0; off >>= 1) s += __shfl_down(s, off, 64);
    __shared__ unsigned wsum[4];
    if ((t & 63) == 0) wsum[t >> 6] = s;
    __syncthreads();
    if (t == 0) blockSums[blockIdx.x] = wsum[0] + wsum[1] + wsum[2] + wsum[3];
}

// 3) combined[word] = {bits, exclusive prefix popcount}
__global__ void k_build_combined(const uint4* __restrict__ bm4, const unsigned* __restrict__ blockSums,
                                 uint4* __restrict__ combined4) {
    int t = threadIdx.x, lane = t & 63;
    __shared__ unsigned preW[4];
    __shared__ unsigned wsum[4];

    unsigned pre = 0;
    for (int i = t; i < blockIdx.x; i += 256) pre += blockSums[i];
    for (int off = 32; off > 0; off >>= 1) pre += __shfl_down(pre, off, 64);
    if (lane == 0) preW[t >> 6] = pre;
    __syncthreads();
    unsigned blockBase = preW[0] + preW[1] + preW[2] + preW[3];

    int gw = blockIdx.x * 256 + t;
    uint4 w = bm4[gw];
    unsigned p0 = __popc(w.x), p1 = __popc(w.y), p2 = __popc(w.z), p3 = __popc(w.w);
    unsigned s = p0 + p1 + p2 + p3;
    unsigned incl = s;
    for (int off = 1; off < 64; off <<= 1) {
        unsigned u = __shfl_up(incl, off, 64);
        if (lane >= off) incl += u;
    }
    if (lane == 63) wsum[t >> 6] = incl;
    __syncthreads();
    unsigned waveBase = 0;
    int wv = t >> 6;
    for (int i = 0; i < wv; i++) waveBase += wsum[i];
    unsigned excl = blockBase + waveBase + incl - s;
    uint4 a; a.x = w.x; a.y = excl;           a.z = w.y; a.w = excl + p0;
    uint4 b; b.x = w.z; b.y = excl + p0 + p1; b.z = w.w; b.w = excl + p0 + p1 + p2;
    combined4[gw * 2 + 0] = a;
    combined4[gw * 2 + 1] = b;
}

__device__ __forceinline__ unsigned rank_of(unsigned key, const uint2* __restrict__ combined) {
    uint2 cw = combined[key >> 5];
    unsigned bit = key & 31u;
    return cw.y + __popc(cw.x & ((1u << bit) - 1u));
}

// 4) FUSED rank+gather, scatter-WRITE, 4 points/thread: four fully independent
//    coords->rank->write chains in flight per thread (round-5 counters: 2-pt
//    version ran at 3.37 TB/s, VALUBusy 6% -> pure chain-latency bound).
__global__ __launch_bounds__(256) void k_scatter_feats(const float* __restrict__ feats,
                                                       const int4* __restrict__ coords,
                                                       const uint2* __restrict__ combined,
                                                       float* __restrict__ sfeats,
                                                       float* __restrict__ outCoordsF, int n) {
    int q = threadIdx.x & 7;
    int i0 = blockIdx.x * 128 + (threadIdx.x >> 3);
    int i1 = i0 + 32, i2 = i0 + 64, i3 = i0 + 96;
    bool v0 = i0 < n, v1 = i1 < n, v2 = i2 < n, v3 = i3 < n;

    int4 c0, c1, c2, c3;
    float4 f0, f1, f2, f3;
    if (v0) c0 = coords[i0];
    if (v1) c1 = coords[i1];
    if (v2) c2 = coords[i2];
    if (v3) c3 = coords[i3];
    if (v0) f0 = ((const float4*)(feats + (size_t)i0 * NPTS_C))[q]; // coalesced
    if (v1) f1 = ((const float4*)(feats + (size_t)i1 * NPTS_C))[q];
    if (v2) f2 = ((const float4*)(feats + (size_t)i2 * NPTS_C))[q];
    if (v3) f3 = ((const float4*)(feats + (size_t)i3 * NPTS_C))[q];

    unsigned r0 = 0, r1 = 0, r2 = 0, r3 = 0;
    if (v0) r0 = rank_of(make_key(c0.x, c0.y, c0.z, c0.w), combined);
    if (v1) r1 = rank_of(make_key(c1.x, c1.y, c1.z, c1.w), combined);
    if (v2) r2 = rank_of(make_key(c2.x, c2.y, c2.z, c2.w), combined);
    if (v3) r3 = rank_of(make_key(c3.x, c3.y, c3.z, c3.w), combined);

    if (v0) ((float4*)(sfeats + (size_t)r0 * NPTS_C))[q] = f0;      // scattered full-row writes
    if (v1) ((float4*)(sfeats + (size_t)r1 * NPTS_C))[q] = f1;
    if (v2) ((float4*)(sfeats + (size_t)r2 * NPTS_C))[q] = f2;
    if (v3) ((float4*)(sfeats + (size_t)r3 * NPTS_C))[q] = f3;
    if (q == 0) {
        if (v0) { float4 fc; fc.x=(float)c0.x; fc.y=(float)c0.y; fc.z=(float)c0.z; fc.w=(float)c0.w; ((float4*)outCoordsF)[r0] = fc; }
        if (v1) { float4 fc; fc.x=(float)c1.x; fc.y=(float)c1.y; fc.z=(float)c1.z; fc.w=(float)c1.w; ((float4*)outCoordsF)[r1] = fc; }
        if (v2) { float4 fc; fc.x=(float)c2.x; fc.y=(float)c2.y; fc.z=(float)c2.z; fc.w=(float)c2.w; ((float4*)outCoordsF)[r2] = fc; }
        if (v3) { float4 fc; fc.x=(float)c3.x; fc.y=(float)c3.y; fc.z=(float)c3.z; fc.w=(float)c3.w; ((float4*)outCoordsF)[r3] = fc; }
    }
}

// 5) conv, phase-split resolve (round-5, verified) + 2-WIDE accumulate walk:
//    pop two mask bits per iteration, two independent rank-local 128B reads
//    back-to-back into two accumulators -> 2x MLP in the serial neighbor walk.
//    VGPR budget: stay under the 64-reg occupancy cliff.
__global__ __launch_bounds__(256) void k_conv_sorted4(const float* __restrict__ sfeats,
                                                      const float* __restrict__ weight,
                                                      const float* __restrict__ outCoordsF,
                                                      const uint2* __restrict__ combined,
                                                      float* __restrict__ out, int n) {
    __shared__ float4 swT4[NTAPS * 9];   // swT4[kk*9+q] = weights for channels 4q..4q+3, tap kk (pad 8->9)
    __shared__ int ldsN[8][4][28];       // [group][round][tap] resolved sorted rank or -1

    int t = threadIdx.x;
    for (int idx = t; idx < NTAPS * 8; idx += 256) {
        int kk = idx >> 3, q = idx & 7;
        float4 w4;
        w4.x = weight[(4 * q + 0) * NTAPS + kk];
        w4.y = weight[(4 * q + 1) * NTAPS + kk];
        w4.z = weight[(4 * q + 2) * NTAPS + kk];
        w4.w = weight[(4 * q + 3) * NTAPS + kk];
        swT4[kk * 9 + q] = w4;
    }

    int gi = t >> 5, l = t & 31;
    bool hi = (t & 32) != 0;
    int p0 = (blockIdx.x * 8 + gi) * 4;  // 4 consecutive ranks per group
    int cluster = l >> 3, q = l & 7;

    // lane constants
    int dxl = l / 9 - 1, dyl = (l % 9) / 3 - 1, dzl = l % 3 - 1;
    int jl = l / 3;                      // probing lane for tap l
    int pbx = l / 3 - 1, pby = l % 3 - 1; // probe (dx,dy) for lanes 0..8

    // ---- Phase 1: all 4 rounds' coords — 4 independent broadcast loads ----
    int cbA[4], cxA[4], cyA[4], czA[4];
    #pragma unroll
    for (int r = 0; r < 4; r++) {
        int pc = min(p0 + r, n - 1);
        float4 cf = ((const float4*)outCoordsF)[pc]; // 4 rounds share one 64B line
        cbA[r] = (int)cf.x; cxA[r] = (int)cf.y; cyA[r] = (int)cf.z; czA[r] = (int)cf.w;
    }

    // ---- Phase 2a: primary probes for all 4 rounds (lanes 0..8) ----
    uint2 cwA[4];
    #pragma unroll
    for (int r = 0; r < 4; r++) {
        uint2 cw; cw.x = 0u; cw.y = 0u;
        if (l < 9) {
            int xj = cxA[r] + pbx, yj = cyA[r] + pby;
            if ((unsigned)xj < 256u && (unsigned)yj < 256u)
                cw = combined[make_key(cbA[r], xj, yj, czA[r]) >> 5];
        }
        cwA[r] = cw;
    }

    // ---- Phase 2b: conditional self-probes (z crossed word boundary) ----
    uint2 spA[4];
    #pragma unroll
    for (int r = 0; r < 4; r++) {
        int x = cxA[r] + dxl, y = cyA[r] + dyl, z = czA[r] + dzl;
        bool ok = (l < NTAPS) && (l != 13) &&
                  (unsigned)x < 256u && (unsigned)y < 256u && (unsigned)z < 256u;
        bool sp = ok && ((z >> 5) != (czA[r] >> 5));
        uint2 t2; t2.x = 0u; t2.y = 0u;
        if (sp) t2 = combined[make_key(cbA[r], x, y, z) >> 5];
        spA[r] = t2;
    }

    // ---- center-tap prefetch: latency hides under phase 3 + barrier ----
    int pm = p0 + cluster;
    float4 fc_c; fc_c.x = fc_c.y = fc_c.z = fc_c.w = 0.0f;
    if (pm < n) fc_c = ((const float4*)(sfeats + (size_t)pm * NPTS_C))[q];

    // ---- Phase 3: pure ALU/shuffle/ballot/LDS (no new memory latency) ----
    unsigned mk[4];
    #pragma unroll
    for (int r = 0; r < 4; r++) {
        unsigned bb = __shfl(cwA[r].x, jl, 32);
        unsigned pp = __shfl(cwA[r].y, jl, 32);
        int x = cxA[r] + dxl, y = cyA[r] + dyl, z = czA[r] + dzl;
        bool ok = (l < NTAPS) && (l != 13) &&
                  (unsigned)x < 256u && (unsigned)y < 256u && (unsigned)z < 256u;
        bool sp = ok && ((z >> 5) != (czA[r] >> 5));
        if (sp) { bb = spA[r].x; pp = spA[r].y; }
        int nidx = -1;
        if (ok) {
            unsigned keyk = make_key(cbA[r], x, y, z);
            unsigned bit = keyk & 31u;
            if ((bb >> bit) & 1u)
                nidx = (int)(pp + __popc(bb & ((1u << bit) - 1u)));
        }
        unsigned long long bal = __ballot(nidx >= 0);
        mk[r] = hi ? (unsigned)(bal >> 32) : (unsigned)bal;
        if (l < NTAPS) ldsN[gi][r][l] = nidx;
    }
    __syncthreads(); // covers swT4 fill + ldsN writes

    float4 acc; acc.x = acc.y = acc.z = acc.w = 0.0f;
    float4 acc2; acc2.x = acc2.y = acc2.z = acc2.w = 0.0f;
    if (pm < n) { // center tap from prefetched row
        float4 w4 = swT4[13 * 9 + q];
        acc.x = fc_c.x * w4.x; acc.y = fc_c.y * w4.y; acc.z = fc_c.z * w4.z; acc.w = fc_c.w * w4.w;
    }

    unsigned m = mk[cluster]; // cluster-uniform mask, ~13.5 set bits avg
    int cnt = __popc(m);
    while (cnt >= 2) {        // 2-wide: two independent rank-local reads in flight
        int k0 = __ffs(m) - 1; m &= m - 1;
        int k1 = __ffs(m) - 1; m &= m - 1;
        cnt -= 2;
        int g0 = ldsN[gi][cluster][k0];
        int g1 = ldsN[gi][cluster][k1];
        float4 f0 = ((const float4*)(sfeats + (size_t)g0 * NPTS_C))[q];
        float4 f1 = ((const float4*)(sfeats + (size_t)g1 * NPTS_C))[q];
        float4 w0 = swT4[k0 * 9 + q];
        float4 w1 = swT4[k1 * 9 + q];
        acc.x  += f0.x * w0.x; acc.y  += f0.y * w0.y; acc.z  += f0.z * w0.z; acc.w  += f0.w * w0.w;
        acc2.x += f1.x * w1.x; acc2.y += f1.y * w1.y; acc2.z += f1.z * w1.z; acc2.w += f1.w * w1.w;
    }
    if (cnt) {                // at most one leftover
        int kk = __ffs(m) - 1;
        int g = ldsN[gi][cluster][kk];
        float4 f = ((const float4*)(sfeats + (size_t)g * NPTS_C))[q];
        float4 w4 = swT4[kk * 9 + q];
        acc.x += f.x * w4.x; acc.y += f.y * w4.y; acc.z += f.z * w4.z; acc.w += f.w * w4.w;
    }
    if (pm < n) {
        f32x4 v;
        v.x = acc.x + acc2.x; v.y = acc.y + acc2.y; v.z = acc.z + acc2.z; v.w = acc.w + acc2.w;
        f32x4* dst = (f32x4*)(out + (size_t)pm * NPTS_C);
        __builtin_nontemporal_store(v, &dst[q]);
    }
}

// ---------------- FALLBACK (small ws) ----------------
__global__ void k_scatter_rank(const int4* __restrict__ coords, const uint2* __restrict__ combined,
                               int* __restrict__ origOf, int n) {
    int i = blockIdx.x * blockDim.x + threadIdx.x;
    if (i >= n) return;
    int4 co = coords[i];
    unsigned r = rank_of(make_key(co.x, co.y, co.z, co.w), combined);
    origOf[r] = i;
}

__device__ __forceinline__ int resolve_tap(int cb, int cx, int cy, int cz, int k,
                                           const uint2* __restrict__ combined) {
    int dx = k / 9 - 1, dy = (k % 9) / 3 - 1, dz = k % 3 - 1;
    int x = cx + dx, y = cy + dy, z = cz + dz;
    bool valid = (k < NTAPS) && ((unsigned)x < 256u) && ((unsigned)y < 256u) && ((unsigned)z < 256u);
    uint2 cw; cw.x = 0u; cw.y = 0u;
    if (k < 9) {
        int dxj = k / 3 - 1, dyj = k % 3 - 1;
        int xj = cx + dxj, yj = cy + dyj;
        if ((unsigned)xj < 256u && (unsigned)yj < 256u)
            cw = combined[make_key(cb, xj, yj, cz) >> 5];
    }
    int j = k / 3;
    unsigned bb = __shfl(cw.x, j, 32);
    unsigned pp = __shfl(cw.y, j, 32);
    int nidx = -1;
    if (valid) {
        unsigned keyk = make_key(cb, x, y, z);
        if ((z >> 5) != (cz >> 5)) {
            uint2 t2 = combined[keyk >> 5];
            bb = t2.x; pp = t2.y;
        }
        unsigned bit = keyk & 31u;
        if ((bb >> bit) & 1u)
            nidx = (int)(pp + __popc(bb & ((1u << bit) - 1u)));
    }
    return nidx;
}

__global__ __launch_bounds__(256) void k_conv_indirect(const float* __restrict__ feats, const float* __restrict__ weight,
                                                       const int4* __restrict__ coords,
                                                       const uint2* __restrict__ combined,
                                                       const int* __restrict__ origOf,
                                                       float* __restrict__ out, float* __restrict__ outCoordsF, int n) {
    __shared__ float swT[NTAPS * 32];
    for (int idx = threadIdx.x; idx < NTAPS * 32; idx += 256) {
        int kk = idx >> 5, cc = idx & 31;
        swT[idx] = weight[cc * NTAPS + kk];
    }
    __syncthreads();

    int p = blockIdx.x * 8 + (threadIdx.x >> 5);
    int c = threadIdx.x & 31;
    if (p >= n) return;

    int orig = origOf[p];
    int4 co = coords[orig];
    if (c == 0) {
        float4 f; f.x = (float)co.x; f.y = (float)co.y; f.z = (float)co.z; f.w = (float)co.w;
        ((float4*)outCoordsF)[p] = f;
    }

    int nidx0 = resolve_tap(co.x, co.y, co.z, co.w, c, combined);
    int nidx = (nidx0 >= 0) ? origOf[nidx0] : -1;

    unsigned long long full = __ballot(nidx >= 0);
    unsigned mymask = (threadIdx.x & 32) ? (unsigned)(full >> 32) : (unsigned)full;

    float acc = 0.0f;
    while (mymask) {
        int kk = __ffs(mymask) - 1;
        mymask &= mymask - 1;
        int g = __shfl(nidx, kk, 32);
        acc += feats[(size_t)g * NPTS_C + c] * swT[kk * 32 + c];
    }
    out[(size_t)p * NPTS_C + c] = acc;
}

extern "C" void kernel_launch(void* const* d_in, const int* in_sizes, int n_in,
                              void* d_out, int out_size, void* d_ws, size_t ws_size,
                              hipStream_t stream) {
    const float* feats  = (const float*)d_in[0];
    const int4*  coords = (const int4*)d_in[1];
    const float* weight = (const float*)d_in[2];
    const int n = in_sizes[1] / 4;

    float* out        = (float*)d_out;              // [N, 32] f32
    float* outCoordsF = (float*)d_out + n * NPTS_C; // [N, 4] float values

    char* ws = (char*)d_ws;
    unsigned* bitmask   = (unsigned*)ws;                               // 4 MB (reused as origOf in fallback)
    uint2*    combined  = (uint2*)(ws + (size_t)KEY_WORDS * 4);        // 8 MB
    unsigned* blockSums = (unsigned*)(ws + (size_t)KEY_WORDS * 12);    // 4 KB
    char*     rest      = ws + (size_t)KEY_WORDS * 12 + 4096;

    size_t need_big = (size_t)KEY_WORDS * 12 + 4096 + (size_t)n * NPTS_C * 4;
    bool big = ws_size >= need_big;

    (void)hipMemsetAsync(bitmask, 0, (size_t)KEY_WORDS * 4, stream);

    int tb = 256;
    k_scatter_bits<<<(n + tb - 1) / tb, tb, 0, stream>>>(coords, bitmask, n);
    k_popc_sums<<<SCAN_BLOCKS, 256, 0, stream>>>((const uint4*)bitmask, blockSums);
    k_build_combined<<<SCAN_BLOCKS, 256, 0, stream>>>((const uint4*)bitmask, blockSums, (uint4*)combined);

    if (big) {
        float* sfeats = (float*)rest; // N*32 f32 = 76.8 MB
        k_scatter_feats<<<(n + 127) / 128, 256, 0, stream>>>(feats, coords, combined,
                                                             sfeats, outCoordsF, n);
        k_conv_sorted4<<<(n + 31) / 32, 256, 0, stream>>>(sfeats, weight, outCoordsF, combined, out, n);
    } else {
        int* origOf = (int*)bitmask; // bitmask dead after k_build_combined; N*4 <= 4 MB
        k_scatter_rank<<<(n + tb - 1) / tb, tb, 0, stream>>>(coords, combined, origOf, n);
        k_conv_indirect<<<(n + 7) / 8, 256, 0, stream>>>(feats, weight, coords, combined, origOf, out, outCoordsF, n);
    }
}

// Round 7
// 243.259 us; speedup vs baseline: 1.0059x; 1.0059x over previous
//
#include <hip/hip_runtime.h>

#define NPTS_C 32            // channels
#define NTAPS 27             // 3x3x3
#define KEY_WORDS (1u << 20) // 2^25 keys / 32 bits
#define SCAN_BLOCKS 1024     // KEY_WORDS / 1024 words per block

typedef float f32x4 __attribute__((ext_vector_type(4))); // native vec for nontemporal store

__device__ __forceinline__ unsigned make_key(int b, int x, int y, int z) {
    return ((((unsigned)b << 8 | (unsigned)x) << 8 | (unsigned)y) << 8) | (unsigned)z;
}

// 1) scatter occupancy bits
__global__ void k_scatter_bits(const int4* __restrict__ coords, unsigned* __restrict__ bitmask, int n) {
    int i = blockIdx.x * blockDim.x + threadIdx.x;
    if (i >= n) return;
    int4 co = coords[i];
    unsigned key = make_key(co.x, co.y, co.z, co.w);
    atomicOr(&bitmask[key >> 5], 1u << (key & 31u));
}

// 2) per-block (1024 words) popcount sums
__global__ void k_popc_sums(const uint4* __restrict__ bm4, unsigned* __restrict__ blockSums) {
    int t = threadIdx.x;
    uint4 w = bm4[blockIdx.x * 256 + t];
    unsigned s = __popc(w.x) + __popc(w.y) + __popc(w.z) + __popc(w.w);
    for (int off = 32; off > 0; off >>= 1) s += __shfl_down(s, off, 64);
    __shared__ unsigned wsum[4];
    if ((t & 63) == 0) wsum[t >> 6] = s;
    __syncthreads();
    if (t == 0) blockSums[blockIdx.x] = wsum[0] + wsum[1] + wsum[2] + wsum[3];
}

// 3) combined[word] = {bits, exclusive prefix popcount}
__global__ void k_build_combined(const uint4* __restrict__ bm4, const unsigned* __restrict__ blockSums,
                                 uint4* __restrict__ combined4) {
    int t = threadIdx.x, lane = t & 63;
    __shared__ unsigned preW[4];
    __shared__ unsigned wsum[4];

    unsigned pre = 0;
    for (int i = t; i < blockIdx.x; i += 256) pre += blockSums[i];
    for (int off = 32; off > 0; off >>= 1) pre += __shfl_down(pre, off, 64);
    if (lane == 0) preW[t >> 6] = pre;
    __syncthreads();
    unsigned blockBase = preW[0] + preW[1] + preW[2] + preW[3];

    int gw = blockIdx.x * 256 + t;
    uint4 w = bm4[gw];
    unsigned p0 = __popc(w.x), p1 = __popc(w.y), p2 = __popc(w.z), p3 = __popc(w.w);
    unsigned s = p0 + p1 + p2 + p3;
    unsigned incl = s;
    for (int off = 1; off < 64; off <<= 1) {
        unsigned u = __shfl_up(incl, off, 64);
        if (lane >= off) incl += u;
    }
    if (lane == 63) wsum[t >> 6] = incl;
    __syncthreads();
    unsigned waveBase = 0;
    int wv = t >> 6;
    for (int i = 0; i < wv; i++) waveBase += wsum[i];
    unsigned excl = blockBase + waveBase + incl - s;
    uint4 a; a.x = w.x; a.y = excl;           a.z = w.y; a.w = excl + p0;
    uint4 b; b.x = w.z; b.y = excl + p0 + p1; b.z = w.w; b.w = excl + p0 + p1 + p2;
    combined4[gw * 2 + 0] = a;
    combined4[gw * 2 + 1] = b;
}

__device__ __forceinline__ unsigned rank_of(unsigned key, const uint2* __restrict__ combined) {
    uint2 cw = combined[key >> 5];
    unsigned bit = key & 31u;
    return cw.y + __popc(cw.x & ((1u << bit) - 1u));
}

// 4) FUSED rank+gather, scatter-WRITE, 2 points/thread (round-5 verified 52.3 us;
//    round-6 showed 4-pt regresses: near the scattered-128B-write efficiency wall,
//    extra streams only thrash).
__global__ __launch_bounds__(256) void k_scatter_feats(const float* __restrict__ feats,
                                                       const int4* __restrict__ coords,
                                                       const uint2* __restrict__ combined,
                                                       float* __restrict__ sfeats,
                                                       float* __restrict__ outCoordsF, int n) {
    int q = threadIdx.x & 7;
    int i0 = blockIdx.x * 64 + (threadIdx.x >> 3); // first point
    int i1 = i0 + 32;                              // second point
    bool vA = i0 < n, vB = i1 < n;

    int4 coA, coB;
    float4 fA, fB;
    if (vA) coA = coords[i0];
    if (vB) coB = coords[i1];
    if (vA) fA = ((const float4*)(feats + (size_t)i0 * NPTS_C))[q]; // coalesced
    if (vB) fB = ((const float4*)(feats + (size_t)i1 * NPTS_C))[q]; // coalesced

    unsigned rA = 0, rB = 0;
    if (vA) rA = rank_of(make_key(coA.x, coA.y, coA.z, coA.w), combined);
    if (vB) rB = rank_of(make_key(coB.x, coB.y, coB.z, coB.w), combined);

    if (vA) {
        ((float4*)(sfeats + (size_t)rA * NPTS_C))[q] = fA;          // scattered full-row write
        if (q == 0) {
            float4 fc; fc.x = (float)coA.x; fc.y = (float)coA.y; fc.z = (float)coA.z; fc.w = (float)coA.w;
            ((float4*)outCoordsF)[rA] = fc;
        }
    }
    if (vB) {
        ((float4*)(sfeats + (size_t)rB * NPTS_C))[q] = fB;
        if (q == 0) {
            float4 fc; fc.x = (float)coB.x; fc.y = (float)coB.y; fc.z = (float)coB.z; fc.w = (float)coB.w;
            ((float4*)outCoordsF)[rB] = fc;
        }
    }
}

// 5) conv: phase-split resolve (round-5, verified) + COMPACTED LIST + 4-wide
//    SOFTWARE-PIPELINED walk: resolve writes a dense tap list (ballot+popc
//    position, padded to x4 with zero-weight dummy tap 27); the walk is a
//    2-stage rotation — issue next-4 row loads before consuming current-4,
//    so 8 rank-local 128B reads are in flight per thread (explicit named
//    registers, no runtime-indexed arrays).
__global__ __launch_bounds__(256) void k_conv_sorted4(const float* __restrict__ sfeats,
                                                      const float* __restrict__ weight,
                                                      const float* __restrict__ outCoordsF,
                                                      const uint2* __restrict__ combined,
                                                      float* __restrict__ out, int n) {
    __shared__ float4 swT4[28 * 9];      // 28 taps (27 real + zero dummy), pad 8->9
    __shared__ __attribute__((aligned(16))) int ldsL[8][4][28]; // [group][round][slot] packed nidx<<5|kk
    __shared__ int ldsCnt[8][4];         // x4-padded list length

    int t = threadIdx.x;
    for (int idx = t; idx < 28 * 8; idx += 256) {
        int kk = idx >> 3, q = idx & 7;
        float4 w4;
        if (kk < NTAPS) {
            w4.x = weight[(4 * q + 0) * NTAPS + kk];
            w4.y = weight[(4 * q + 1) * NTAPS + kk];
            w4.z = weight[(4 * q + 2) * NTAPS + kk];
            w4.w = weight[(4 * q + 3) * NTAPS + kk];
        } else {
            w4.x = w4.y = w4.z = w4.w = 0.0f;             // dummy tap 27: zero weight
        }
        swT4[kk * 9 + q] = w4;
    }

    int gi = t >> 5, l = t & 31;
    bool hi = (t & 32) != 0;
    int p0 = (blockIdx.x * 8 + gi) * 4;  // 4 consecutive ranks per group
    int cluster = l >> 3, q = l & 7;

    // lane constants
    int dxl = l / 9 - 1, dyl = (l % 9) / 3 - 1, dzl = l % 3 - 1;
    int jl = l / 3;                      // probing lane for tap l
    int pbx = l / 3 - 1, pby = l % 3 - 1; // probe (dx,dy) for lanes 0..8

    // ---- Phase 1: all 4 rounds' coords — 4 independent broadcast loads ----
    int cbA[4], cxA[4], cyA[4], czA[4];
    #pragma unroll
    for (int r = 0; r < 4; r++) {
        int pc = min(p0 + r, n - 1);
        float4 cf = ((const float4*)outCoordsF)[pc]; // 4 rounds share one 64B line
        cbA[r] = (int)cf.x; cxA[r] = (int)cf.y; cyA[r] = (int)cf.z; czA[r] = (int)cf.w;
    }

    // ---- Phase 2a: primary probes for all 4 rounds (lanes 0..8) ----
    uint2 cwA[4];
    #pragma unroll
    for (int r = 0; r < 4; r++) {
        uint2 cw; cw.x = 0u; cw.y = 0u;
        if (l < 9) {
            int xj = cxA[r] + pbx, yj = cyA[r] + pby;
            if ((unsigned)xj < 256u && (unsigned)yj < 256u)
                cw = combined[make_key(cbA[r], xj, yj, czA[r]) >> 5];
        }
        cwA[r] = cw;
    }

    // ---- Phase 2b: conditional self-probes (z crossed word boundary) ----
    uint2 spA[4];
    #pragma unroll
    for (int r = 0; r < 4; r++) {
        int x = cxA[r] + dxl, y = cyA[r] + dyl, z = czA[r] + dzl;
        bool ok = (l < NTAPS) && (l != 13) &&
                  (unsigned)x < 256u && (unsigned)y < 256u && (unsigned)z < 256u;
        bool sp = ok && ((z >> 5) != (czA[r] >> 5));
        uint2 t2; t2.x = 0u; t2.y = 0u;
        if (sp) t2 = combined[make_key(cbA[r], x, y, z) >> 5];
        spA[r] = t2;
    }

    // ---- center-tap prefetch: latency hides under phase 3 + barrier ----
    int pm = p0 + cluster;
    float4 fc_c; fc_c.x = fc_c.y = fc_c.z = fc_c.w = 0.0f;
    if (pm < n) fc_c = ((const float4*)(sfeats + (size_t)pm * NPTS_C))[q];

    // ---- Phase 3: pure ALU/shuffle/ballot/LDS; write COMPACTED list ----
    #pragma unroll
    for (int r = 0; r < 4; r++) {
        unsigned bb = __shfl(cwA[r].x, jl, 32);
        unsigned pp = __shfl(cwA[r].y, jl, 32);
        int x = cxA[r] + dxl, y = cyA[r] + dyl, z = czA[r] + dzl;
        bool ok = (l < NTAPS) && (l != 13) &&
                  (unsigned)x < 256u && (unsigned)y < 256u && (unsigned)z < 256u;
        bool sp = ok && ((z >> 5) != (czA[r] >> 5));
        if (sp) { bb = spA[r].x; pp = spA[r].y; }
        int nidx = -1;
        if (ok) {
            unsigned keyk = make_key(cbA[r], x, y, z);
            unsigned bit = keyk & 31u;
            if ((bb >> bit) & 1u)
                nidx = (int)(pp + __popc(bb & ((1u << bit) - 1u)));
        }
        unsigned long long bal = __ballot(nidx >= 0);
        unsigned mymask = hi ? (unsigned)(bal >> 32) : (unsigned)bal;
        unsigned pos = __popc(mymask & ((1u << l) - 1u));
        unsigned cnt = __popc(mymask);
        unsigned cnt4 = (cnt + 3u) & ~3u;
        if (nidx >= 0) ldsL[gi][r][pos] = (nidx << 5) | l;   // compacted write
        if (l == 0) ldsCnt[gi][r] = (int)cnt4;
        else if (l >= NTAPS && l < 31) {                     // lanes 27..30: pads
            unsigned idx = cnt + (unsigned)(l - NTAPS);
            if (idx < cnt4) ldsL[gi][r][idx] = 27;           // row 0, tap 27 (w=0)
        }
    }
    __syncthreads(); // covers swT4 fill + ldsL/ldsCnt writes

    float4 acc0; acc0.x = acc0.y = acc0.z = acc0.w = 0.0f;
    float4 acc1 = acc0;
    if (pm < n) { // center tap from prefetched row
        float4 w4 = swT4[13 * 9 + q];
        acc0.x = fc_c.x * w4.x; acc0.y = fc_c.y * w4.y; acc0.z = fc_c.z * w4.z; acc0.w = fc_c.w * w4.w;
    }

    int cnt4 = ldsCnt[gi][cluster];
    const int* lst = &ldsL[gi][cluster][0];

    if (cnt4 > 0) {
        // 2-stage pipelined 4-wide walk: 8 rank-local 128B reads in flight.
        int4 vc = *(const int4*)&lst[0];
        float4 f0 = ((const float4*)(sfeats + (size_t)(unsigned)(vc.x >> 5) * NPTS_C))[q];
        float4 f1 = ((const float4*)(sfeats + (size_t)(unsigned)(vc.y >> 5) * NPTS_C))[q];
        float4 f2 = ((const float4*)(sfeats + (size_t)(unsigned)(vc.z >> 5) * NPTS_C))[q];
        float4 f3 = ((const float4*)(sfeats + (size_t)(unsigned)(vc.w >> 5) * NPTS_C))[q];
        for (int i = 4; i < cnt4; i += 4) {
            int4 vn = *(const int4*)&lst[i];                 // next indices
            float4 g0 = ((const float4*)(sfeats + (size_t)(unsigned)(vn.x >> 5) * NPTS_C))[q];
            float4 g1 = ((const float4*)(sfeats + (size_t)(unsigned)(vn.y >> 5) * NPTS_C))[q];
            float4 g2 = ((const float4*)(sfeats + (size_t)(unsigned)(vn.z >> 5) * NPTS_C))[q];
            float4 g3 = ((const float4*)(sfeats + (size_t)(unsigned)(vn.w >> 5) * NPTS_C))[q];
            float4 w0 = swT4[(vc.x & 31) * 9 + q];
            float4 w1 = swT4[(vc.y & 31) * 9 + q];
            float4 w2 = swT4[(vc.z & 31) * 9 + q];
            float4 w3 = swT4[(vc.w & 31) * 9 + q];
            acc0.x += f0.x * w0.x; acc0.y += f0.y * w0.y; acc0.z += f0.z * w0.z; acc0.w += f0.w * w0.w;
            acc1.x += f1.x * w1.x; acc1.y += f1.y * w1.y; acc1.z += f1.z * w1.z; acc1.w += f1.w * w1.w;
            acc0.x += f2.x * w2.x; acc0.y += f2.y * w2.y; acc0.z += f2.z * w2.z; acc0.w += f2.w * w2.w;
            acc1.x += f3.x * w3.x; acc1.y += f3.y * w3.y; acc1.z += f3.z * w3.z; acc1.w += f3.w * w3.w;
            vc = vn; f0 = g0; f1 = g1; f2 = g2; f3 = g3;
        }
        float4 w0 = swT4[(vc.x & 31) * 9 + q];
        float4 w1 = swT4[(vc.y & 31) * 9 + q];
        float4 w2 = swT4[(vc.z & 31) * 9 + q];
        float4 w3 = swT4[(vc.w & 31) * 9 + q];
        acc0.x += f0.x * w0.x; acc0.y += f0.y * w0.y; acc0.z += f0.z * w0.z; acc0.w += f0.w * w0.w;
        acc1.x += f1.x * w1.x; acc1.y += f1.y * w1.y; acc1.z += f1.z * w1.z; acc1.w += f1.w * w1.w;
        acc0.x += f2.x * w2.x; acc0.y += f2.y * w2.y; acc0.z += f2.z * w2.z; acc0.w += f2.w * w2.w;
        acc1.x += f3.x * w3.x; acc1.y += f3.y * w3.y; acc1.z += f3.z * w3.z; acc1.w += f3.w * w3.w;
    }

    if (pm < n) {
        f32x4 v;
        v.x = acc0.x + acc1.x; v.y = acc0.y + acc1.y; v.z = acc0.z + acc1.z; v.w = acc0.w + acc1.w;
        f32x4* dst = (f32x4*)(out + (size_t)pm * NPTS_C);
        __builtin_nontemporal_store(v, &dst[q]);
    }
}

// ---------------- FALLBACK (small ws) ----------------
__global__ void k_scatter_rank(const int4* __restrict__ coords, const uint2* __restrict__ combined,
                               int* __restrict__ origOf, int n) {
    int i = blockIdx.x * blockDim.x + threadIdx.x;
    if (i >= n) return;
    int4 co = coords[i];
    unsigned r = rank_of(make_key(co.x, co.y, co.z, co.w), combined);
    origOf[r] = i;
}

__device__ __forceinline__ int resolve_tap(int cb, int cx, int cy, int cz, int k,
                                           const uint2* __restrict__ combined) {
    int dx = k / 9 - 1, dy = (k % 9) / 3 - 1, dz = k % 3 - 1;
    int x = cx + dx, y = cy + dy, z = cz + dz;
    bool valid = (k < NTAPS) && ((unsigned)x < 256u) && ((unsigned)y < 256u) && ((unsigned)z < 256u);
    uint2 cw; cw.x = 0u; cw.y = 0u;
    if (k < 9) {
        int dxj = k / 3 - 1, dyj = k % 3 - 1;
        int xj = cx + dxj, yj = cy + dyj;
        if ((unsigned)xj < 256u && (unsigned)yj < 256u)
            cw = combined[make_key(cb, xj, yj, cz) >> 5];
    }
    int j = k / 3;
    unsigned bb = __shfl(cw.x, j, 32);
    unsigned pp = __shfl(cw.y, j, 32);
    int nidx = -1;
    if (valid) {
        unsigned keyk = make_key(cb, x, y, z);
        if ((z >> 5) != (cz >> 5)) {
            uint2 t2 = combined[keyk >> 5];
            bb = t2.x; pp = t2.y;
        }
        unsigned bit = keyk & 31u;
        if ((bb >> bit) & 1u)
            nidx = (int)(pp + __popc(bb & ((1u << bit) - 1u)));
    }
    return nidx;
}

__global__ __launch_bounds__(256) void k_conv_indirect(const float* __restrict__ feats, const float* __restrict__ weight,
                                                       const int4* __restrict__ coords,
                                                       const uint2* __restrict__ combined,
                                                       const int* __restrict__ origOf,
                                                       float* __restrict__ out, float* __restrict__ outCoordsF, int n) {
    __shared__ float swT[NTAPS * 32];
    for (int idx = threadIdx.x; idx < NTAPS * 32; idx += 256) {
        int kk = idx >> 5, cc = idx & 31;
        swT[idx] = weight[cc * NTAPS + kk];
    }
    __syncthreads();

    int p = blockIdx.x * 8 + (threadIdx.x >> 5);
    int c = threadIdx.x & 31;
    if (p >= n) return;

    int orig = origOf[p];
    int4 co = coords[orig];
    if (c == 0) {
        float4 f; f.x = (float)co.x; f.y = (float)co.y; f.z = (float)co.z; f.w = (float)co.w;
        ((float4*)outCoordsF)[p] = f;
    }

    int nidx0 = resolve_tap(co.x, co.y, co.z, co.w, c, combined);
    int nidx = (nidx0 >= 0) ? origOf[nidx0] : -1;

    unsigned long long full = __ballot(nidx >= 0);
    unsigned mymask = (threadIdx.x & 32) ? (unsigned)(full >> 32) : (unsigned)full;

    float acc = 0.0f;
    while (mymask) {
        int kk = __ffs(mymask) - 1;
        mymask &= mymask - 1;
        int g = __shfl(nidx, kk, 32);
        acc += feats[(size_t)g * NPTS_C + c] * swT[kk * 32 + c];
    }
    out[(size_t)p * NPTS_C + c] = acc;
}

extern "C" void kernel_launch(void* const* d_in, const int* in_sizes, int n_in,
                              void* d_out, int out_size, void* d_ws, size_t ws_size,
                              hipStream_t stream) {
    const float* feats  = (const float*)d_in[0];
    const int4*  coords = (const int4*)d_in[1];
    const float* weight = (const float*)d_in[2];
    const int n = in_sizes[1] / 4;

    float* out        = (float*)d_out;              // [N, 32] f32
    float* outCoordsF = (float*)d_out + n * NPTS_C; // [N, 4] float values

    char* ws = (char*)d_ws;
    unsigned* bitmask   = (unsigned*)ws;                               // 4 MB (reused as origOf in fallback)
    uint2*    combined  = (uint2*)(ws + (size_t)KEY_WORDS * 4);        // 8 MB
    unsigned* blockSums = (unsigned*)(ws + (size_t)KEY_WORDS * 12);    // 4 KB
    char*     rest      = ws + (size_t)KEY_WORDS * 12 + 4096;

    size_t need_big = (size_t)KEY_WORDS * 12 + 4096 + (size_t)n * NPTS_C * 4;
    bool big = ws_size >= need_big;

    (void)hipMemsetAsync(bitmask, 0, (size_t)KEY_WORDS * 4, stream);

    int tb = 256;
    k_scatter_bits<<<(n + tb - 1) / tb, tb, 0, stream>>>(coords, bitmask, n);
    k_popc_sums<<<SCAN_BLOCKS, 256, 0, stream>>>((const uint4*)bitmask, blockSums);
    k_build_combined<<<SCAN_BLOCKS, 256, 0, stream>>>((const uint4*)bitmask, blockSums, (uint4*)combined);

    if (big) {
        float* sfeats = (float*)rest; // N*32 f32 = 76.8 MB
        k_scatter_feats<<<(n + 63) / 64, 256, 0, stream>>>(feats, coords, combined,
                                                           sfeats, outCoordsF, n);
        k_conv_sorted4<<<(n + 31) / 32, 256, 0, stream>>>(sfeats, weight, outCoordsF, combined, out, n);
    } else {
        int* origOf = (int*)bitmask; // bitmask dead after k_build_combined; N*4 <= 4 MB
        k_scatter_rank<<<(n + tb - 1) / tb, tb, 0, stream>>>(coords, combined, origOf, n);
        k_conv_indirect<<<(n + 7) / 8, 256, 0, stream>>>(feats, weight, coords, combined, origOf, out, outCoordsF, n);
    }
}

// Round 8
// 237.824 us; speedup vs baseline: 1.0289x; 1.0228x over previous
//
#include <hip/hip_runtime.h>

#define NPTS_C 32            // channels
#define NTAPS 27             // 3x3x3
#define KEY_WORDS (1u << 20) // 2^25 keys / 32 bits
#define SCAN_BLOCKS 1024     // KEY_WORDS / 1024 words per block

typedef float f32x4 __attribute__((ext_vector_type(4))); // native vec for nontemporal store

__device__ __forceinline__ unsigned make_key(int b, int x, int y, int z) {
    return ((((unsigned)b << 8 | (unsigned)x) << 8 | (unsigned)y) << 8) | (unsigned)z;
}

// 1) scatter occupancy bits
__global__ void k_scatter_bits(const int4* __restrict__ coords, unsigned* __restrict__ bitmask, int n) {
    int i = blockIdx.x * blockDim.x + threadIdx.x;
    if (i >= n) return;
    int4 co = coords[i];
    unsigned key = make_key(co.x, co.y, co.z, co.w);
    atomicOr(&bitmask[key >> 5], 1u << (key & 31u));
}

// 2) per-block (1024 words) popcount sums
__global__ void k_popc_sums(const uint4* __restrict__ bm4, unsigned* __restrict__ blockSums) {
    int t = threadIdx.x;
    uint4 w = bm4[blockIdx.x * 256 + t];
    unsigned s = __popc(w.x) + __popc(w.y) + __popc(w.z) + __popc(w.w);
    for (int off = 32; off > 0; off >>= 1) s += __shfl_down(s, off, 64);
    __shared__ unsigned wsum[4];
    if ((t & 63) == 0) wsum[t >> 6] = s;
    __syncthreads();
    if (t == 0) blockSums[blockIdx.x] = wsum[0] + wsum[1] + wsum[2] + wsum[3];
}

// 3) combined[word] = {bits, exclusive prefix popcount}
__global__ void k_build_combined(const uint4* __restrict__ bm4, const unsigned* __restrict__ blockSums,
                                 uint4* __restrict__ combined4) {
    int t = threadIdx.x, lane = t & 63;
    __shared__ unsigned preW[4];
    __shared__ unsigned wsum[4];

    unsigned pre = 0;
    for (int i = t; i < blockIdx.x; i += 256) pre += blockSums[i];
    for (int off = 32; off > 0; off >>= 1) pre += __shfl_down(pre, off, 64);
    if (lane == 0) preW[t >> 6] = pre;
    __syncthreads();
    unsigned blockBase = preW[0] + preW[1] + preW[2] + preW[3];

    int gw = blockIdx.x * 256 + t;
    uint4 w = bm4[gw];
    unsigned p0 = __popc(w.x), p1 = __popc(w.y), p2 = __popc(w.z), p3 = __popc(w.w);
    unsigned s = p0 + p1 + p2 + p3;
    unsigned incl = s;
    for (int off = 1; off < 64; off <<= 1) {
        unsigned u = __shfl_up(incl, off, 64);
        if (lane >= off) incl += u;
    }
    if (lane == 63) wsum[t >> 6] = incl;
    __syncthreads();
    unsigned waveBase = 0;
    int wv = t >> 6;
    for (int i = 0; i < wv; i++) waveBase += wsum[i];
    unsigned excl = blockBase + waveBase + incl - s;
    uint4 a; a.x = w.x; a.y = excl;           a.z = w.y; a.w = excl + p0;
    uint4 b; b.x = w.z; b.y = excl + p0 + p1; b.z = w.w; b.w = excl + p0 + p1 + p2;
    combined4[gw * 2 + 0] = a;
    combined4[gw * 2 + 1] = b;
}

__device__ __forceinline__ unsigned rank_of(unsigned key, const uint2* __restrict__ combined) {
    uint2 cw = combined[key >> 5];
    unsigned bit = key & 31u;
    return cw.y + __popc(cw.x & ((1u << bit) - 1u));
}

// 4) FUSED rank+gather, scatter-WRITE, 2 points/thread (round-5 verified 52.3 us;
//    round-6 proved 4-pt regresses: near the scattered-write efficiency wall).
__global__ __launch_bounds__(256) void k_scatter_feats(const float* __restrict__ feats,
                                                       const int4* __restrict__ coords,
                                                       const uint2* __restrict__ combined,
                                                       float* __restrict__ sfeats,
                                                       float* __restrict__ outCoordsF, int n) {
    int q = threadIdx.x & 7;
    int i0 = blockIdx.x * 64 + (threadIdx.x >> 3); // first point
    int i1 = i0 + 32;                              // second point
    bool vA = i0 < n, vB = i1 < n;

    int4 coA, coB;
    float4 fA, fB;
    if (vA) coA = coords[i0];
    if (vB) coB = coords[i1];
    if (vA) fA = ((const float4*)(feats + (size_t)i0 * NPTS_C))[q]; // coalesced
    if (vB) fB = ((const float4*)(feats + (size_t)i1 * NPTS_C))[q]; // coalesced

    unsigned rA = 0, rB = 0;
    if (vA) rA = rank_of(make_key(coA.x, coA.y, coA.z, coA.w), combined);
    if (vB) rB = rank_of(make_key(coB.x, coB.y, coB.z, coB.w), combined);

    if (vA) {
        ((float4*)(sfeats + (size_t)rA * NPTS_C))[q] = fA;          // scattered full-row write
        if (q == 0) {
            float4 fc; fc.x = (float)coA.x; fc.y = (float)coA.y; fc.z = (float)coA.z; fc.w = (float)coA.w;
            ((float4*)outCoordsF)[rA] = fc;
        }
    }
    if (vB) {
        ((float4*)(sfeats + (size_t)rB * NPTS_C))[q] = fB;
        if (q == 0) {
            float4 fc; fc.x = (float)coB.x; fc.y = (float)coB.y; fc.z = (float)coB.z; fc.w = (float)coB.w;
            ((float4*)outCoordsF)[rB] = fc;
        }
    }
}

// 5) conv: round-5 verified form (phase-split resolve + simple mask walk +
//    center prefetch) + XCD-aware bijective block swizzle (T1): consecutive
//    rank windows share tap rows; chunking the grid per-XCD keeps those
//    overlapping reads in one XCD's private L2 instead of re-fetching from L3.
//    (Round-7 lesson: compacted-list/pipelined walk turns this VALU-bound —
//    keep the walk lean.)
__global__ __launch_bounds__(256) void k_conv_sorted4(const float* __restrict__ sfeats,
                                                      const float* __restrict__ weight,
                                                      const float* __restrict__ outCoordsF,
                                                      const uint2* __restrict__ combined,
                                                      float* __restrict__ out, int n) {
    __shared__ float4 swT4[NTAPS * 9];   // swT4[kk*9+q] = weights for channels 4q..4q+3, tap kk (pad 8->9)
    __shared__ int ldsN[8][4][28];       // [group][round][tap] resolved sorted rank or -1

    int t = threadIdx.x;
    for (int idx = t; idx < NTAPS * 8; idx += 256) {
        int kk = idx >> 3, q = idx & 7;
        float4 w4;
        w4.x = weight[(4 * q + 0) * NTAPS + kk];
        w4.y = weight[(4 * q + 1) * NTAPS + kk];
        w4.z = weight[(4 * q + 2) * NTAPS + kk];
        w4.w = weight[(4 * q + 3) * NTAPS + kk];
        swT4[kk * 9 + q] = w4;
    }

    // ---- XCD-aware bijective swizzle (m204 formula; grid % 8 != 0 safe) ----
    int nwg = gridDim.x;
    int q8 = nwg >> 3, r8 = nwg & 7;
    int xcd = blockIdx.x & 7, idx8 = blockIdx.x >> 3;
    int bid = (xcd < r8) ? xcd * (q8 + 1) + idx8
                         : r8 * (q8 + 1) + (xcd - r8) * q8 + idx8;

    int gi = t >> 5, l = t & 31;
    bool hi = (t & 32) != 0;
    int p0 = (bid * 8 + gi) * 4;         // 4 consecutive ranks per group
    int cluster = l >> 3, q = l & 7;

    // lane constants
    int dxl = l / 9 - 1, dyl = (l % 9) / 3 - 1, dzl = l % 3 - 1;
    int jl = l / 3;                      // probing lane for tap l
    int pbx = l / 3 - 1, pby = l % 3 - 1; // probe (dx,dy) for lanes 0..8

    // ---- Phase 1: all 4 rounds' coords — 4 independent broadcast loads ----
    int cbA[4], cxA[4], cyA[4], czA[4];
    #pragma unroll
    for (int r = 0; r < 4; r++) {
        int pc = min(p0 + r, n - 1);
        float4 cf = ((const float4*)outCoordsF)[pc]; // 4 rounds share one 64B line
        cbA[r] = (int)cf.x; cxA[r] = (int)cf.y; cyA[r] = (int)cf.z; czA[r] = (int)cf.w;
    }

    // ---- Phase 2a: primary probes for all 4 rounds (lanes 0..8) ----
    uint2 cwA[4];
    #pragma unroll
    for (int r = 0; r < 4; r++) {
        uint2 cw; cw.x = 0u; cw.y = 0u;
        if (l < 9) {
            int xj = cxA[r] + pbx, yj = cyA[r] + pby;
            if ((unsigned)xj < 256u && (unsigned)yj < 256u)
                cw = combined[make_key(cbA[r], xj, yj, czA[r]) >> 5];
        }
        cwA[r] = cw;
    }

    // ---- Phase 2b: conditional self-probes (z crossed word boundary) ----
    uint2 spA[4];
    #pragma unroll
    for (int r = 0; r < 4; r++) {
        int x = cxA[r] + dxl, y = cyA[r] + dyl, z = czA[r] + dzl;
        bool ok = (l < NTAPS) && (l != 13) &&
                  (unsigned)x < 256u && (unsigned)y < 256u && (unsigned)z < 256u;
        bool sp = ok && ((z >> 5) != (czA[r] >> 5));
        uint2 t2; t2.x = 0u; t2.y = 0u;
        if (sp) t2 = combined[make_key(cbA[r], x, y, z) >> 5];
        spA[r] = t2;
    }

    // ---- center-tap prefetch: latency hides under phase 3 + barrier ----
    int pm = p0 + cluster;
    float4 fc_c; fc_c.x = fc_c.y = fc_c.z = fc_c.w = 0.0f;
    if (pm < n) fc_c = ((const float4*)(sfeats + (size_t)pm * NPTS_C))[q];

    // ---- Phase 3: pure ALU/shuffle/ballot/LDS (no new memory latency) ----
    unsigned mk[4];
    #pragma unroll
    for (int r = 0; r < 4; r++) {
        unsigned bb = __shfl(cwA[r].x, jl, 32);
        unsigned pp = __shfl(cwA[r].y, jl, 32);
        int x = cxA[r] + dxl, y = cyA[r] + dyl, z = czA[r] + dzl;
        bool ok = (l < NTAPS) && (l != 13) &&
                  (unsigned)x < 256u && (unsigned)y < 256u && (unsigned)z < 256u;
        bool sp = ok && ((z >> 5) != (czA[r] >> 5));
        if (sp) { bb = spA[r].x; pp = spA[r].y; }
        int nidx = -1;
        if (ok) {
            unsigned keyk = make_key(cbA[r], x, y, z);
            unsigned bit = keyk & 31u;
            if ((bb >> bit) & 1u)
                nidx = (int)(pp + __popc(bb & ((1u << bit) - 1u)));
        }
        unsigned long long bal = __ballot(nidx >= 0);
        mk[r] = hi ? (unsigned)(bal >> 32) : (unsigned)bal;
        if (l < NTAPS) ldsN[gi][r][l] = nidx;
    }
    __syncthreads(); // covers swT4 fill + ldsN writes

    float4 acc; acc.x = acc.y = acc.z = acc.w = 0.0f;
    if (pm < n) { // center tap from prefetched row
        float4 w4 = swT4[13 * 9 + q];
        acc.x = fc_c.x * w4.x; acc.y = fc_c.y * w4.y; acc.z = fc_c.z * w4.z; acc.w = fc_c.w * w4.w;
    }

    unsigned m = mk[cluster]; // cluster-uniform mask, ~13.5 set bits avg
    while (m) {
        int kk = __ffs(m) - 1; m &= m - 1;
        int g = ldsN[gi][cluster][kk];                        // broadcast ds_read
        float4 f = ((const float4*)(sfeats + (size_t)g * NPTS_C))[q]; // rank-local 128B row
        float4 w4 = swT4[kk * 9 + q];
        acc.x += f.x * w4.x; acc.y += f.y * w4.y; acc.z += f.z * w4.z; acc.w += f.w * w4.w;
    }
    if (pm < n) {
        f32x4 v; v.x = acc.x; v.y = acc.y; v.z = acc.z; v.w = acc.w;
        f32x4* dst = (f32x4*)(out + (size_t)pm * NPTS_C);
        __builtin_nontemporal_store(v, &dst[q]);
    }
}

// ---------------- FALLBACK (small ws) ----------------
__global__ void k_scatter_rank(const int4* __restrict__ coords, const uint2* __restrict__ combined,
                               int* __restrict__ origOf, int n) {
    int i = blockIdx.x * blockDim.x + threadIdx.x;
    if (i >= n) return;
    int4 co = coords[i];
    unsigned r = rank_of(make_key(co.x, co.y, co.z, co.w), combined);
    origOf[r] = i;
}

__device__ __forceinline__ int resolve_tap(int cb, int cx, int cy, int cz, int k,
                                           const uint2* __restrict__ combined) {
    int dx = k / 9 - 1, dy = (k % 9) / 3 - 1, dz = k % 3 - 1;
    int x = cx + dx, y = cy + dy, z = cz + dz;
    bool valid = (k < NTAPS) && ((unsigned)x < 256u) && ((unsigned)y < 256u) && ((unsigned)z < 256u);
    uint2 cw; cw.x = 0u; cw.y = 0u;
    if (k < 9) {
        int dxj = k / 3 - 1, dyj = k % 3 - 1;
        int xj = cx + dxj, yj = cy + dyj;
        if ((unsigned)xj < 256u && (unsigned)yj < 256u)
            cw = combined[make_key(cb, xj, yj, cz) >> 5];
    }
    int j = k / 3;
    unsigned bb = __shfl(cw.x, j, 32);
    unsigned pp = __shfl(cw.y, j, 32);
    int nidx = -1;
    if (valid) {
        unsigned keyk = make_key(cb, x, y, z);
        if ((z >> 5) != (cz >> 5)) {
            uint2 t2 = combined[keyk >> 5];
            bb = t2.x; pp = t2.y;
        }
        unsigned bit = keyk & 31u;
        if ((bb >> bit) & 1u)
            nidx = (int)(pp + __popc(bb & ((1u << bit) - 1u)));
    }
    return nidx;
}

__global__ __launch_bounds__(256) void k_conv_indirect(const float* __restrict__ feats, const float* __restrict__ weight,
                                                       const int4* __restrict__ coords,
                                                       const uint2* __restrict__ combined,
                                                       const int* __restrict__ origOf,
                                                       float* __restrict__ out, float* __restrict__ outCoordsF, int n) {
    __shared__ float swT[NTAPS * 32];
    for (int idx = threadIdx.x; idx < NTAPS * 32; idx += 256) {
        int kk = idx >> 5, cc = idx & 31;
        swT[idx] = weight[cc * NTAPS + kk];
    }
    __syncthreads();

    int p = blockIdx.x * 8 + (threadIdx.x >> 5);
    int c = threadIdx.x & 31;
    if (p >= n) return;

    int orig = origOf[p];
    int4 co = coords[orig];
    if (c == 0) {
        float4 f; f.x = (float)co.x; f.y = (float)co.y; f.z = (float)co.z; f.w = (float)co.w;
        ((float4*)outCoordsF)[p] = f;
    }

    int nidx0 = resolve_tap(co.x, co.y, co.z, co.w, c, combined);
    int nidx = (nidx0 >= 0) ? origOf[nidx0] : -1;

    unsigned long long full = __ballot(nidx >= 0);
    unsigned mymask = (threadIdx.x & 32) ? (unsigned)(full >> 32) : (unsigned)full;

    float acc = 0.0f;
    while (mymask) {
        int kk = __ffs(mymask) - 1;
        mymask &= mymask - 1;
        int g = __shfl(nidx, kk, 32);
        acc += feats[(size_t)g * NPTS_C + c] * swT[kk * 32 + c];
    }
    out[(size_t)p * NPTS_C + c] = acc;
}

extern "C" void kernel_launch(void* const* d_in, const int* in_sizes, int n_in,
                              void* d_out, int out_size, void* d_ws, size_t ws_size,
                              hipStream_t stream) {
    const float* feats  = (const float*)d_in[0];
    const int4*  coords = (const int4*)d_in[1];
    const float* weight = (const float*)d_in[2];
    const int n = in_sizes[1] / 4;

    float* out        = (float*)d_out;              // [N, 32] f32
    float* outCoordsF = (float*)d_out + n * NPTS_C; // [N, 4] float values

    char* ws = (char*)d_ws;
    unsigned* bitmask   = (unsigned*)ws;                               // 4 MB (reused as origOf in fallback)
    uint2*    combined  = (uint2*)(ws + (size_t)KEY_WORDS * 4);        // 8 MB
    unsigned* blockSums = (unsigned*)(ws + (size_t)KEY_WORDS * 12);    // 4 KB
    char*     rest      = ws + (size_t)KEY_WORDS * 12 + 4096;

    size_t need_big = (size_t)KEY_WORDS * 12 + 4096 + (size_t)n * NPTS_C * 4;
    bool big = ws_size >= need_big;

    (void)hipMemsetAsync(bitmask, 0, (size_t)KEY_WORDS * 4, stream);

    int tb = 256;
    k_scatter_bits<<<(n + tb - 1) / tb, tb, 0, stream>>>(coords, bitmask, n);
    k_popc_sums<<<SCAN_BLOCKS, 256, 0, stream>>>((const uint4*)bitmask, blockSums);
    k_build_combined<<<SCAN_BLOCKS, 256, 0, stream>>>((const uint4*)bitmask, blockSums, (uint4*)combined);

    if (big) {
        float* sfeats = (float*)rest; // N*32 f32 = 76.8 MB
        k_scatter_feats<<<(n + 63) / 64, 256, 0, stream>>>(feats, coords, combined,
                                                           sfeats, outCoordsF, n);
        k_conv_sorted4<<<(n + 31) / 32, 256, 0, stream>>>(sfeats, weight, outCoordsF, combined, out, n);
    } else {
        int* origOf = (int*)bitmask; // bitmask dead after k_build_combined; N*4 <= 4 MB
        k_scatter_rank<<<(n + tb - 1) / tb, tb, 0, stream>>>(coords, combined, origOf, n);
        k_conv_indirect<<<(n + 7) / 8, 256, 0, stream>>>(feats, weight, coords, combined, origOf, out, outCoordsF, n);
    }
}

// Round 9
// 229.178 us; speedup vs baseline: 1.0677x; 1.0377x over previous
//
#include <hip/hip_runtime.h>

#define NPTS_C 32            // channels
#define NTAPS 27             // 3x3x3
#define KEY_WORDS (1u << 20) // 2^25 keys / 32 bits
#define SCAN_BLOCKS 1024     // KEY_WORDS / 1024 words per block

typedef float f32x4 __attribute__((ext_vector_type(4))); // native vec for nontemporal store

__device__ __forceinline__ unsigned make_key(int b, int x, int y, int z) {
    return ((((unsigned)b << 8 | (unsigned)x) << 8 | (unsigned)y) << 8) | (unsigned)z;
}

__device__ __forceinline__ unsigned sel4u(int c, unsigned a0, unsigned a1, unsigned a2, unsigned a3) {
    return c == 0 ? a0 : c == 1 ? a1 : c == 2 ? a2 : a3;
}
__device__ __forceinline__ int sel4i(int c, int a0, int a1, int a2, int a3) {
    return c == 0 ? a0 : c == 1 ? a1 : c == 2 ? a2 : a3;
}

// 1) scatter occupancy bits
__global__ void k_scatter_bits(const int4* __restrict__ coords, unsigned* __restrict__ bitmask, int n) {
    int i = blockIdx.x * blockDim.x + threadIdx.x;
    if (i >= n) return;
    int4 co = coords[i];
    unsigned key = make_key(co.x, co.y, co.z, co.w);
    atomicOr(&bitmask[key >> 5], 1u << (key & 31u));
}

// 2) per-block (1024 words) popcount sums
__global__ void k_popc_sums(const uint4* __restrict__ bm4, unsigned* __restrict__ blockSums) {
    int t = threadIdx.x;
    uint4 w = bm4[blockIdx.x * 256 + t];
    unsigned s = __popc(w.x) + __popc(w.y) + __popc(w.z) + __popc(w.w);
    for (int off = 32; off > 0; off >>= 1) s += __shfl_down(s, off, 64);
    __shared__ unsigned wsum[4];
    if ((t & 63) == 0) wsum[t >> 6] = s;
    __syncthreads();
    if (t == 0) blockSums[blockIdx.x] = wsum[0] + wsum[1] + wsum[2] + wsum[3];
}

// 3) combined[word] = {bits, exclusive prefix popcount}
__global__ void k_build_combined(const uint4* __restrict__ bm4, const unsigned* __restrict__ blockSums,
                                 uint4* __restrict__ combined4) {
    int t = threadIdx.x, lane = t & 63;
    __shared__ unsigned preW[4];
    __shared__ unsigned wsum[4];

    unsigned pre = 0;
    for (int i = t; i < blockIdx.x; i += 256) pre += blockSums[i];
    for (int off = 32; off > 0; off >>= 1) pre += __shfl_down(pre, off, 64);
    if (lane == 0) preW[t >> 6] = pre;
    __syncthreads();
    unsigned blockBase = preW[0] + preW[1] + preW[2] + preW[3];

    int gw = blockIdx.x * 256 + t;
    uint4 w = bm4[gw];
    unsigned p0 = __popc(w.x), p1 = __popc(w.y), p2 = __popc(w.z), p3 = __popc(w.w);
    unsigned s = p0 + p1 + p2 + p3;
    unsigned incl = s;
    for (int off = 1; off < 64; off <<= 1) {
        unsigned u = __shfl_up(incl, off, 64);
        if (lane >= off) incl += u;
    }
    if (lane == 63) wsum[t >> 6] = incl;
    __syncthreads();
    unsigned waveBase = 0;
    int wv = t >> 6;
    for (int i = 0; i < wv; i++) waveBase += wsum[i];
    unsigned excl = blockBase + waveBase + incl - s;
    uint4 a; a.x = w.x; a.y = excl;           a.z = w.y; a.w = excl + p0;
    uint4 b; b.x = w.z; b.y = excl + p0 + p1; b.z = w.w; b.w = excl + p0 + p1 + p2;
    combined4[gw * 2 + 0] = a;
    combined4[gw * 2 + 1] = b;
}

__device__ __forceinline__ unsigned rank_of(unsigned key, const uint2* __restrict__ combined) {
    uint2 cw = combined[key >> 5];
    unsigned bit = key & 31u;
    return cw.y + __popc(cw.x & ((1u << bit) - 1u));
}

// 4) FUSED rank+gather, scatter-WRITE, 2 points/thread (round-5/8 verified 51.6 us;
//    round-6 proved 4-pt regresses: at the scattered-128B-write wall).
__global__ __launch_bounds__(256) void k_scatter_feats(const float* __restrict__ feats,
                                                       const int4* __restrict__ coords,
                                                       const uint2* __restrict__ combined,
                                                       float* __restrict__ sfeats,
                                                       float* __restrict__ outCoordsF, int n) {
    int q = threadIdx.x & 7;
    int i0 = blockIdx.x * 64 + (threadIdx.x >> 3); // first point
    int i1 = i0 + 32;                              // second point
    bool vA = i0 < n, vB = i1 < n;

    int4 coA, coB;
    float4 fA, fB;
    if (vA) coA = coords[i0];
    if (vB) coB = coords[i1];
    if (vA) fA = ((const float4*)(feats + (size_t)i0 * NPTS_C))[q]; // coalesced
    if (vB) fB = ((const float4*)(feats + (size_t)i1 * NPTS_C))[q]; // coalesced

    unsigned rA = 0, rB = 0;
    if (vA) rA = rank_of(make_key(coA.x, coA.y, coA.z, coA.w), combined);
    if (vB) rB = rank_of(make_key(coB.x, coB.y, coB.z, coB.w), combined);

    if (vA) {
        ((float4*)(sfeats + (size_t)rA * NPTS_C))[q] = fA;          // scattered full-row write
        if (q == 0) {
            float4 fc; fc.x = (float)coA.x; fc.y = (float)coA.y; fc.z = (float)coA.z; fc.w = (float)coA.w;
            ((float4*)outCoordsF)[rA] = fc;
        }
    }
    if (vB) {
        ((float4*)(sfeats + (size_t)rB * NPTS_C))[q] = fB;
        if (q == 0) {
            float4 fc; fc.x = (float)coB.x; fc.y = (float)coB.y; fc.z = (float)coB.z; fc.w = (float)coB.w;
            ((float4*)outCoordsF)[rB] = fc;
        }
    }
}

// 5) conv, 8-RANK groups + direct per-lane probes + LDS-free shfl walk:
//    - 8 consecutive ranks per 32-lane group (2 points walked per lane):
//      halves resolve-chain latency per point, doubles store streams/wave.
//    - each tap lane probes combined[] for its OWN key (no 9-lane broadcast,
//      no z-crossing special case, no shfl stage in resolve).
//    - walk gets neighbor rank via __shfl of the resolving lane's register
//      (k_conv_indirect precedent) -> no ldsN, removes ~120cy LDS hop from
//      the walk's dependent chain. ~0.47 avg set bits/mask -> walk is cheap.
//    - XCD-aware bijective swizzle (round-8, verified).
__global__ __launch_bounds__(256) void k_conv_sorted8(const float* __restrict__ sfeats,
                                                      const float* __restrict__ weight,
                                                      const float* __restrict__ outCoordsF,
                                                      const uint2* __restrict__ combined,
                                                      float* __restrict__ out, int n) {
    __shared__ float4 swT4[NTAPS * 9];   // swT4[kk*9+q] = weights for channels 4q..4q+3, tap kk (pad 8->9)

    int t = threadIdx.x;
    for (int idx = t; idx < NTAPS * 8; idx += 256) {
        int kk = idx >> 3, q = idx & 7;
        float4 w4;
        w4.x = weight[(4 * q + 0) * NTAPS + kk];
        w4.y = weight[(4 * q + 1) * NTAPS + kk];
        w4.z = weight[(4 * q + 2) * NTAPS + kk];
        w4.w = weight[(4 * q + 3) * NTAPS + kk];
        swT4[kk * 9 + q] = w4;
    }

    // ---- XCD-aware bijective swizzle (m204 formula; grid % 8 != 0 safe) ----
    int nwg = gridDim.x;
    int q8 = nwg >> 3, r8 = nwg & 7;
    int xcd = blockIdx.x & 7, idx8 = blockIdx.x >> 3;
    int bid = (xcd < r8) ? xcd * (q8 + 1) + idx8
                         : r8 * (q8 + 1) + (xcd - r8) * q8 + idx8;

    int gi = t >> 5, l = t & 31;
    bool hi = (t & 32) != 0;
    int p0 = (bid * 8 + gi) * 8;         // 8 consecutive ranks per 32-lane group
    int cluster = l >> 3, q = l & 7;

    // lane's tap offset
    int dxl = l / 9 - 1, dyl = (l % 9) / 3 - 1, dzl = l % 3 - 1;
    bool lane_tap = (l < NTAPS) && (l != 13);

    // ---- center prefetch (earliest, longest-latency independent loads) ----
    int pmA = p0 + cluster, pmB = p0 + 4 + cluster;
    float4 fcA; fcA.x = fcA.y = fcA.z = fcA.w = 0.0f;
    float4 fcB = fcA;
    if (pmA < n) fcA = ((const float4*)(sfeats + (size_t)pmA * NPTS_C))[q];
    if (pmB < n) fcB = ((const float4*)(sfeats + (size_t)pmB * NPTS_C))[q];

    // ---- Phase 1: 8 rounds' coords (2 cache lines, broadcast) ----
    int4 co[8];
    #pragma unroll
    for (int r = 0; r < 8; r++) {
        int pc = min(p0 + r, n - 1);
        float4 cf = ((const float4*)outCoordsF)[pc];
        co[r].x = (int)cf.x; co[r].y = (int)cf.y; co[r].z = (int)cf.z; co[r].w = (int)cf.w;
    }

    // ---- Phase 2: own-key probes, 8 independent loads per tap lane ----
    unsigned key[8]; bool ok[8]; uint2 cw[8];
    #pragma unroll
    for (int r = 0; r < 8; r++) {
        int x = co[r].y + dxl, y = co[r].z + dyl, z = co[r].w + dzl;
        ok[r] = lane_tap && (unsigned)x < 256u && (unsigned)y < 256u && (unsigned)z < 256u;
        key[r] = make_key(co[r].x, x & 255, y & 255, z & 255); // masked: safe addr even when !ok
        cw[r] = combined[ok[r] ? (key[r] >> 5) : 0u];
    }

    // ---- Phase 3: pure ALU — nidx + ballots ----
    int nn[8]; unsigned mk[8];
    #pragma unroll
    for (int r = 0; r < 8; r++) {
        unsigned bit = key[r] & 31u;
        int nid = -1;
        if (ok[r] && ((cw[r].x >> bit) & 1u))
            nid = (int)(cw[r].y + __popc(cw[r].x & ((1u << bit) - 1u)));
        nn[r] = nid;
        unsigned long long bal = __ballot(nid >= 0);
        mk[r] = hi ? (unsigned)(bal >> 32) : (unsigned)bal;
    }
    __syncthreads(); // swT4 ready

    // ---- walk: 2 points per lane, shfl-based neighbor ranks ----
    float4 accA; accA.x = accA.y = accA.z = accA.w = 0.0f;
    float4 accB = accA;
    {
        float4 w13 = swT4[13 * 9 + q];
        if (pmA < n) { accA.x = fcA.x * w13.x; accA.y = fcA.y * w13.y; accA.z = fcA.z * w13.z; accA.w = fcA.w * w13.w; }
        if (pmB < n) { accB.x = fcB.x * w13.x; accB.y = fcB.y * w13.y; accB.z = fcB.z * w13.z; accB.w = fcB.w * w13.w; }
    }

    unsigned mA = sel4u(cluster, mk[0], mk[1], mk[2], mk[3]);
    unsigned mB = sel4u(cluster, mk[4], mk[5], mk[6], mk[7]);
    while (mA) {
        int kk = __ffs(mA) - 1; mA &= mA - 1;
        int g0 = __shfl(nn[0], kk, 32);
        int g1 = __shfl(nn[1], kk, 32);
        int g2 = __shfl(nn[2], kk, 32);
        int g3 = __shfl(nn[3], kk, 32);
        int g = sel4i(cluster, g0, g1, g2, g3);
        float4 f = ((const float4*)(sfeats + (size_t)g * NPTS_C))[q];
        float4 w4 = swT4[kk * 9 + q];
        accA.x += f.x * w4.x; accA.y += f.y * w4.y; accA.z += f.z * w4.z; accA.w += f.w * w4.w;
    }
    while (mB) {
        int kk = __ffs(mB) - 1; mB &= mB - 1;
        int g4 = __shfl(nn[4], kk, 32);
        int g5 = __shfl(nn[5], kk, 32);
        int g6 = __shfl(nn[6], kk, 32);
        int g7 = __shfl(nn[7], kk, 32);
        int g = sel4i(cluster, g4, g5, g6, g7);
        float4 f = ((const float4*)(sfeats + (size_t)g * NPTS_C))[q];
        float4 w4 = swT4[kk * 9 + q];
        accB.x += f.x * w4.x; accB.y += f.y * w4.y; accB.z += f.z * w4.z; accB.w += f.w * w4.w;
    }

    if (pmA < n) {
        f32x4 v; v.x = accA.x; v.y = accA.y; v.z = accA.z; v.w = accA.w;
        __builtin_nontemporal_store(v, &((f32x4*)(out + (size_t)pmA * NPTS_C))[q]);
    }
    if (pmB < n) {
        f32x4 v; v.x = accB.x; v.y = accB.y; v.z = accB.z; v.w = accB.w;
        __builtin_nontemporal_store(v, &((f32x4*)(out + (size_t)pmB * NPTS_C))[q]);
    }
}

// ---------------- FALLBACK (small ws) ----------------
__global__ void k_scatter_rank(const int4* __restrict__ coords, const uint2* __restrict__ combined,
                               int* __restrict__ origOf, int n) {
    int i = blockIdx.x * blockDim.x + threadIdx.x;
    if (i >= n) return;
    int4 co = coords[i];
    unsigned r = rank_of(make_key(co.x, co.y, co.z, co.w), combined);
    origOf[r] = i;
}

__device__ __forceinline__ int resolve_tap(int cb, int cx, int cy, int cz, int k,
                                           const uint2* __restrict__ combined) {
    int dx = k / 9 - 1, dy = (k % 9) / 3 - 1, dz = k % 3 - 1;
    int x = cx + dx, y = cy + dy, z = cz + dz;
    bool valid = (k < NTAPS) && ((unsigned)x < 256u) && ((unsigned)y < 256u) && ((unsigned)z < 256u);
    uint2 cw; cw.x = 0u; cw.y = 0u;
    if (k < 9) {
        int dxj = k / 3 - 1, dyj = k % 3 - 1;
        int xj = cx + dxj, yj = cy + dyj;
        if ((unsigned)xj < 256u && (unsigned)yj < 256u)
            cw = combined[make_key(cb, xj, yj, cz) >> 5];
    }
    int j = k / 3;
    unsigned bb = __shfl(cw.x, j, 32);
    unsigned pp = __shfl(cw.y, j, 32);
    int nidx = -1;
    if (valid) {
        unsigned keyk = make_key(cb, x, y, z);
        if ((z >> 5) != (cz >> 5)) {
            uint2 t2 = combined[keyk >> 5];
            bb = t2.x; pp = t2.y;
        }
        unsigned bit = keyk & 31u;
        if ((bb >> bit) & 1u)
            nidx = (int)(pp + __popc(bb & ((1u << bit) - 1u)));
    }
    return nidx;
}

__global__ __launch_bounds__(256) void k_conv_indirect(const float* __restrict__ feats, const float* __restrict__ weight,
                                                       const int4* __restrict__ coords,
                                                       const uint2* __restrict__ combined,
                                                       const int* __restrict__ origOf,
                                                       float* __restrict__ out, float* __restrict__ outCoordsF, int n) {
    __shared__ float swT[NTAPS * 32];
    for (int idx = threadIdx.x; idx < NTAPS * 32; idx += 256) {
        int kk = idx >> 5, cc = idx & 31;
        swT[idx] = weight[cc * NTAPS + kk];
    }
    __syncthreads();

    int p = blockIdx.x * 8 + (threadIdx.x >> 5);
    int c = threadIdx.x & 31;
    if (p >= n) return;

    int orig = origOf[p];
    int4 co = coords[orig];
    if (c == 0) {
        float4 f; f.x = (float)co.x; f.y = (float)co.y; f.z = (float)co.z; f.w = (float)co.w;
        ((float4*)outCoordsF)[p] = f;
    }

    int nidx0 = resolve_tap(co.x, co.y, co.z, co.w, c, combined);
    int nidx = (nidx0 >= 0) ? origOf[nidx0] : -1;

    unsigned long long full = __ballot(nidx >= 0);
    unsigned mymask = (threadIdx.x & 32) ? (unsigned)(full >> 32) : (unsigned)full;

    float acc = 0.0f;
    while (mymask) {
        int kk = __ffs(mymask) - 1;
        mymask &= mymask - 1;
        int g = __shfl(nidx, kk, 32);
        acc += feats[(size_t)g * NPTS_C + c] * swT[kk * 32 + c];
    }
    out[(size_t)p * NPTS_C + c] = acc;
}

extern "C" void kernel_launch(void* const* d_in, const int* in_sizes, int n_in,
                              void* d_out, int out_size, void* d_ws, size_t ws_size,
                              hipStream_t stream) {
    const float* feats  = (const float*)d_in[0];
    const int4*  coords = (const int4*)d_in[1];
    const float* weight = (const float*)d_in[2];
    const int n = in_sizes[1] / 4;

    float* out        = (float*)d_out;              // [N, 32] f32
    float* outCoordsF = (float*)d_out + n * NPTS_C; // [N, 4] float values

    char* ws = (char*)d_ws;
    unsigned* bitmask   = (unsigned*)ws;                               // 4 MB (reused as origOf in fallback)
    uint2*    combined  = (uint2*)(ws + (size_t)KEY_WORDS * 4);        // 8 MB
    unsigned* blockSums = (unsigned*)(ws + (size_t)KEY_WORDS * 12);    // 4 KB
    char*     rest      = ws + (size_t)KEY_WORDS * 12 + 4096;

    size_t need_big = (size_t)KEY_WORDS * 12 + 4096 + (size_t)n * NPTS_C * 4;
    bool big = ws_size >= need_big;

    (void)hipMemsetAsync(bitmask, 0, (size_t)KEY_WORDS * 4, stream);

    int tb = 256;
    k_scatter_bits<<<(n + tb - 1) / tb, tb, 0, stream>>>(coords, bitmask, n);
    k_popc_sums<<<SCAN_BLOCKS, 256, 0, stream>>>((const uint4*)bitmask, blockSums);
    k_build_combined<<<SCAN_BLOCKS, 256, 0, stream>>>((const uint4*)bitmask, blockSums, (uint4*)combined);

    if (big) {
        float* sfeats = (float*)rest; // N*32 f32 = 76.8 MB
        k_scatter_feats<<<(n + 63) / 64, 256, 0, stream>>>(feats, coords, combined,
                                                           sfeats, outCoordsF, n);
        k_conv_sorted8<<<(n + 63) / 64, 256, 0, stream>>>(sfeats, weight, outCoordsF, combined, out, n);
    } else {
        int* origOf = (int*)bitmask; // bitmask dead after k_build_combined; N*4 <= 4 MB
        k_scatter_rank<<<(n + tb - 1) / tb, tb, 0, stream>>>(coords, combined, origOf, n);
        k_conv_indirect<<<(n + 7) / 8, 256, 0, stream>>>(feats, weight, coords, combined, origOf, out, outCoordsF, n);
    }
}